// Round 1
// baseline (2074.978 us; speedup 1.0000x reference)
//
#include <hip/hip_runtime.h>

typedef _Float16 h2_t __attribute__((ext_vector_type(2)));
typedef _Float16 h4_t __attribute__((ext_vector_type(4)));
typedef _Float16 h8_t __attribute__((ext_vector_type(8)));
typedef float    f4_t __attribute__((ext_vector_type(4)));

#define B_  64
#define T_  512
#define F_  128
#define H_  512

static __device__ __forceinline__ float fdot2f(h2_t a, h2_t b, float c) {
#if __has_builtin(__builtin_amdgcn_fdot2)
    return __builtin_amdgcn_fdot2(a, b, c, false);
#else
    return c + (float)a.x * (float)b.x + (float)a.y * (float)b.y;
#endif
}

// ---------------- prep kernels ----------------
__global__ void k_cast_f16(const float* __restrict__ src, _Float16* __restrict__ dst, int n) {
    int i = blockIdx.x * blockDim.x + threadIdx.x;
    if (i < n) dst[i] = (_Float16)src[i];
}

// Wz[c][k] = Wih_de[c][512+k];  Wr[c][k] = Wih_de[c][k] + Whh_de[c][k]
__global__ void k_prep_de(const float* __restrict__ Wih_de, const float* __restrict__ Whh_de,
                          _Float16* __restrict__ Wz, _Float16* __restrict__ Wr) {
    int i = blockIdx.x * blockDim.x + threadIdx.x;   // over 512*512
    int cc = i >> 9, kk = i & 511;
    Wz[i] = (_Float16)Wih_de[cc * 1024 + 512 + kk];
    Wr[i] = (_Float16)(Wih_de[cc * 1024 + kk] + Whh_de[i]);
}

__global__ void k_prep_bias(const float* __restrict__ a, const float* __restrict__ b,
                            float* __restrict__ o) {
    int i = threadIdx.x;
    o[i] = a[i] + b[i];
}

// ---------------- GEMM: C[M,N] = A[M,K] @ Bt[N,K]^T + bias[N] ----------------
// f16 inputs, f32 accumulate; writes f32 (Cf) and/or f16 (Ch).
#define BM 128
#define BN 128
#define BK 32
#define LDT 40   // padded LDS row stride in f16 units

__global__ __launch_bounds__(256) void k_gemm(
    const _Float16* __restrict__ A, const _Float16* __restrict__ Bt,
    const float* __restrict__ bias,
    float* __restrict__ Cf, _Float16* __restrict__ Ch,
    int M, int N, int K) {
    __shared__ _Float16 Al[BM * LDT];
    __shared__ _Float16 Bl[BN * LDT];
    const int tid = threadIdx.x;
    const int bm = blockIdx.x * BM, bn = blockIdx.y * BN;
    const int wid = tid >> 6, lane = tid & 63;
    const int wm = (wid >> 1) * 64, wn = (wid & 1) * 64;
    const int l15 = lane & 15, l4 = lane >> 4;

    f4_t acc[4][4];
    #pragma unroll
    for (int i = 0; i < 4; ++i)
        #pragma unroll
        for (int j = 0; j < 4; ++j) {
            f4_t zz = {0.f, 0.f, 0.f, 0.f};
            acc[i][j] = zz;
        }

    const int r = tid >> 1, hf = tid & 1;
    const h8_t* gA0 = (const h8_t*)(A + (size_t)(bm + r) * K);
    const h8_t* gB0 = (const h8_t*)(Bt + (size_t)(bn + r) * K);

    for (int k0 = 0; k0 < K; k0 += BK) {
        __syncthreads();
        int kf = (k0 >> 3) + hf * 2;
        h8_t a0 = gA0[kf], a1 = gA0[kf + 1];
        h8_t b0 = gB0[kf], b1 = gB0[kf + 1];
        *(h8_t*)&Al[r * LDT + hf * 16]     = a0;
        *(h8_t*)&Al[r * LDT + hf * 16 + 8] = a1;
        *(h8_t*)&Bl[r * LDT + hf * 16]     = b0;
        *(h8_t*)&Bl[r * LDT + hf * 16 + 8] = b1;
        __syncthreads();
        h8_t af[4], bf[4];
        #pragma unroll
        for (int i = 0; i < 4; ++i) af[i] = *(const h8_t*)&Al[(wm + i * 16 + l15) * LDT + l4 * 8];
        #pragma unroll
        for (int j = 0; j < 4; ++j) bf[j] = *(const h8_t*)&Bl[(wn + j * 16 + l15) * LDT + l4 * 8];
        #pragma unroll
        for (int i = 0; i < 4; ++i)
            #pragma unroll
            for (int j = 0; j < 4; ++j)
                acc[i][j] = __builtin_amdgcn_mfma_f32_16x16x32_f16(af[i], bf[j], acc[i][j], 0, 0, 0);
    }

    #pragma unroll
    for (int i = 0; i < 4; ++i) {
        int m0 = bm + wm + i * 16 + l4 * 4;
        #pragma unroll
        for (int j = 0; j < 4; ++j) {
            int n0 = bn + wn + j * 16 + l15;
            float bb = bias ? bias[n0] : 0.f;
            #pragma unroll
            for (int rr = 0; rr < 4; ++rr) {
                float v = acc[i][j][rr] + bb;
                size_t off = (size_t)(m0 + rr) * N + n0;
                if (Cf) Cf[off] = v;
                if (Ch) Ch[off] = (_Float16)v;
            }
        }
    }
}

// ---------------- persistent-weight RNN ----------------
// One block per batch row. 1024 threads: c = tid&511 (output unit), s = tid>>9 (k-half).
// Weights W[c][k] (f16, row-major [512][512]): per thread, k in [s*256, s*256+192) in
// VGPRs (24 x h8 = 96 regs), k in [s*256+192, s*256+256) in swizzled LDS (128KB total).
// h kept in LDS as f16[512]; 2 barriers per step.
__global__ __launch_bounds__(1024) void k_rnn(
    const _Float16* __restrict__ W,
    const _Float16* __restrict__ pre,   // [B,T,H] f16 pre-activation (x/z contribution + biases)
    _Float16* __restrict__ out) {       // [B,T,H] f16 hidden states
    __shared__ __align__(16) unsigned char WL[131072];
    __shared__ __align__(16) unsigned short h2[H_];
    __shared__ float partial[H_];

    const int tid = threadIdx.x;
    const int c = tid & 511;
    const int s = tid >> 9;
    const int b = blockIdx.x;

    const h8_t* gw = (const h8_t*)(W + (size_t)c * H_ + s * 256);
    h8_t wv[24];
    #pragma unroll
    for (int j = 0; j < 24; ++j) wv[j] = gw[j];
    #pragma unroll
    for (int q = 0; q < 8; ++q) {
        h8_t w = gw[24 + q];
        *(h8_t*)(WL + (c * 256 + s * 128 + ((q * 16) ^ ((c & 7) << 4)))) = w;
    }
    if (tid < 64) ((uint4*)h2)[tid] = make_uint4(0u, 0u, 0u, 0u);
    __syncthreads();

    const size_t baseIdx = (size_t)b * T_ * H_ + c;
    float pcur = (float)pre[baseIdx];

    for (int t = 0; t < T_; ++t) {
        int tn = (t + 1 < T_) ? t + 1 : t;
        _Float16 pnx = pre[baseIdx + (size_t)tn * H_];

        float acc = 0.f;
        const uint4* hv4 = ((const uint4*)h2) + s * 32;
        #pragma unroll
        for (int j = 0; j < 24; ++j) {
            uint4 hh = hv4[j];
            uint4 wu = __builtin_bit_cast(uint4, wv[j]);
            acc = fdot2f(__builtin_bit_cast(h2_t, wu.x), __builtin_bit_cast(h2_t, hh.x), acc);
            acc = fdot2f(__builtin_bit_cast(h2_t, wu.y), __builtin_bit_cast(h2_t, hh.y), acc);
            acc = fdot2f(__builtin_bit_cast(h2_t, wu.z), __builtin_bit_cast(h2_t, hh.z), acc);
            acc = fdot2f(__builtin_bit_cast(h2_t, wu.w), __builtin_bit_cast(h2_t, hh.w), acc);
        }
        #pragma unroll
        for (int q = 0; q < 8; ++q) {
            uint4 wl = *(const uint4*)(WL + (c * 256 + s * 128 + ((q * 16) ^ ((c & 7) << 4))));
            uint4 hh = hv4[24 + q];
            acc = fdot2f(__builtin_bit_cast(h2_t, wl.x), __builtin_bit_cast(h2_t, hh.x), acc);
            acc = fdot2f(__builtin_bit_cast(h2_t, wl.y), __builtin_bit_cast(h2_t, hh.y), acc);
            acc = fdot2f(__builtin_bit_cast(h2_t, wl.z), __builtin_bit_cast(h2_t, hh.z), acc);
            acc = fdot2f(__builtin_bit_cast(h2_t, wl.w), __builtin_bit_cast(h2_t, hh.w), acc);
        }

        if (s) partial[c] = acc;
        __syncthreads();
        if (!s) {
            float tot = acc + partial[c] + pcur;
            float hn = tanhf(tot);
            out[baseIdx + (size_t)t * H_] = (_Float16)hn;
            h2[c] = __builtin_bit_cast(unsigned short, (_Float16)hn);
        }
        __syncthreads();
        pcur = (float)pnx;
    }
}

// ---------------- reparameterize: z = eps * exp(lv/2) + mu ----------------
__global__ void k_z(const float* __restrict__ mu, const float* __restrict__ lv,
                    const float* __restrict__ eps, _Float16* __restrict__ z, int n4) {
    int i = blockIdx.x * blockDim.x + threadIdx.x;
    if (i >= n4) return;
    f4_t m = ((const f4_t*)mu)[i];
    f4_t l = ((const f4_t*)lv)[i];
    f4_t e = ((const f4_t*)eps)[i];
    h4_t r;
    #pragma unroll
    for (int j = 0; j < 4; ++j) r[j] = (_Float16)(e[j] * expf(l[j] * 0.5f) + m[j]);
    ((h4_t*)z)[i] = r;
}

// ---------------- launch ----------------
extern "C" void kernel_launch(void* const* d_in, const int* in_sizes, int n_in,
                              void* d_out, int out_size, void* d_ws, size_t ws_size,
                              hipStream_t stream) {
    const float* x      = (const float*)d_in[0];
    const float* eps    = (const float*)d_in[1];
    const float* Wih_en = (const float*)d_in[2];
    const float* Whh_en = (const float*)d_in[3];
    const float* bih_en = (const float*)d_in[4];
    const float* bhh_en = (const float*)d_in[5];
    const float* W_mu   = (const float*)d_in[6];
    const float* b_mu   = (const float*)d_in[7];
    const float* W_lv   = (const float*)d_in[8];
    const float* b_lv   = (const float*)d_in[9];
    const float* Wih_de = (const float*)d_in[10];
    const float* Whh_de = (const float*)d_in[11];
    const float* bih_de = (const float*)d_in[12];
    const float* bhh_de = (const float*)d_in[13];
    const float* W_mux  = (const float*)d_in[14];
    const float* b_mux  = (const float*)d_in[15];
    const float* W_lvx  = (const float*)d_in[16];
    const float* b_lvx  = (const float*)d_in[17];
    float* out = (float*)d_out;

    char* ws = (char*)d_ws;
    _Float16* Wih_en_h = (_Float16*)(ws + 0);        // 512*128
    _Float16* Whh_en_h = (_Float16*)(ws + 131072);   // 512*512
    _Float16* W_mu_h   = (_Float16*)(ws + 655360);
    _Float16* W_lv_h   = (_Float16*)(ws + 1179648);
    _Float16* Wz_h     = (_Float16*)(ws + 1703936);
    _Float16* Wr_h     = (_Float16*)(ws + 2228224);
    _Float16* Wmux_h   = (_Float16*)(ws + 2752512);  // 128*512
    _Float16* Wlvx_h   = (_Float16*)(ws + 2883584);
    float*    benc     = (float*)(ws + 3014656);     // 512 f32
    float*    bdec     = (float*)(ws + 3016704);
    _Float16* x_h      = (_Float16*)(ws + 4194304);  // 64*512*128
    _Float16* pre_h    = (_Float16*)(ws + 12582912); // 64*512*512  (pre_en, then pre_de)
    _Float16* act_h    = (_Float16*)(ws + 46137344); // 64*512*512  (y, then decoder outputs)
    _Float16* z_h      = (_Float16*)(ws + 79691776); // 64*512*512

    const int thr = 256;
    k_cast_f16<<<(65536 + thr - 1) / thr, thr, 0, stream>>>(Wih_en, Wih_en_h, 65536);
    k_cast_f16<<<(262144 + thr - 1) / thr, thr, 0, stream>>>(Whh_en, Whh_en_h, 262144);
    k_cast_f16<<<(262144 + thr - 1) / thr, thr, 0, stream>>>(W_mu, W_mu_h, 262144);
    k_cast_f16<<<(262144 + thr - 1) / thr, thr, 0, stream>>>(W_lv, W_lv_h, 262144);
    k_cast_f16<<<(65536 + thr - 1) / thr, thr, 0, stream>>>(W_mux, Wmux_h, 65536);
    k_cast_f16<<<(65536 + thr - 1) / thr, thr, 0, stream>>>(W_lvx, Wlvx_h, 65536);
    k_cast_f16<<<(4194304 + thr - 1) / thr, thr, 0, stream>>>(x, x_h, 4194304);
    k_prep_de<<<262144 / thr, thr, 0, stream>>>(Wih_de, Whh_de, Wz_h, Wr_h);
    k_prep_bias<<<1, 512, 0, stream>>>(bih_en, bhh_en, benc);
    k_prep_bias<<<1, 512, 0, stream>>>(bih_de, bhh_de, bdec);

    dim3 gFull(32768 / BM, 512 / BN);   // 256 x 4
    dim3 gNarrow(32768 / BM, 1);        // 256 x 1 (N=128)

    // encoder pre-activation: x @ Wih_en^T + (bih_en + bhh_en)
    k_gemm<<<gFull, 256, 0, stream>>>(x_h, Wih_en_h, benc, nullptr, pre_h, 32768, 512, 128);
    // encoder recurrence -> y
    k_rnn<<<64, 1024, 0, stream>>>(Whh_en_h, pre_h, act_h);
    // mu_post, logsigma2_post
    k_gemm<<<gFull, 256, 0, stream>>>(act_h, W_mu_h, b_mu, out, nullptr, 32768, 512, 512);
    k_gemm<<<gFull, 256, 0, stream>>>(act_h, W_lv_h, b_lv, out + 16777216, nullptr, 32768, 512, 512);
    // z = eps * exp(lv/2) + mu
    k_z<<<4194304 / thr, thr, 0, stream>>>(out, out + 16777216, eps, z_h, 4194304);
    // decoder pre-activation: z @ Wz^T + (bih_de + bhh_de)
    k_gemm<<<gFull, 256, 0, stream>>>(z_h, Wz_h, bdec, nullptr, pre_h, 32768, 512, 512);
    // decoder recurrence -> outputs (reuse act_h; y is dead)
    k_rnn<<<64, 1024, 0, stream>>>(Wr_h, pre_h, act_h);
    // output projections
    k_gemm<<<gNarrow, 256, 0, stream>>>(act_h, Wmux_h, b_mux, out + 33554432, nullptr, 32768, 128, 512);
    k_gemm<<<gNarrow, 256, 0, stream>>>(act_h, Wlvx_h, b_lvx, out + 37748736, nullptr, 32768, 128, 512);
}

// Round 2
// 1807.289 us; speedup vs baseline: 1.1481x; 1.1481x over previous
//
#include <hip/hip_runtime.h>

typedef _Float16 h2_t __attribute__((ext_vector_type(2)));
typedef _Float16 h4_t __attribute__((ext_vector_type(4)));
typedef _Float16 h8_t __attribute__((ext_vector_type(8)));
typedef float    f4_t __attribute__((ext_vector_type(4)));

#define B_  64
#define T_  512
#define F_  128
#define H_  512

static __device__ __forceinline__ float fdot2f(h2_t a, h2_t b, float c) {
#if __has_builtin(__builtin_amdgcn_fdot2)
    return __builtin_amdgcn_fdot2(a, b, c, false);
#else
    return c + (float)a.x * (float)b.x + (float)a.y * (float)b.y;
#endif
}

static __device__ __forceinline__ void dot8(float& acc, uint4 w, uint4 h) {
    acc = fdot2f(__builtin_bit_cast(h2_t, w.x), __builtin_bit_cast(h2_t, h.x), acc);
    acc = fdot2f(__builtin_bit_cast(h2_t, w.y), __builtin_bit_cast(h2_t, h.y), acc);
    acc = fdot2f(__builtin_bit_cast(h2_t, w.z), __builtin_bit_cast(h2_t, h.z), acc);
    acc = fdot2f(__builtin_bit_cast(h2_t, w.w), __builtin_bit_cast(h2_t, h.w), acc);
}

// ---------------- prep kernels ----------------
__global__ void k_cast_f16(const float* __restrict__ src, _Float16* __restrict__ dst, int n) {
    int i = blockIdx.x * blockDim.x + threadIdx.x;
    if (i < n) dst[i] = (_Float16)src[i];
}

// Wz[c][k] = Wih_de[c][512+k];  Wr[c][k] = Wih_de[c][k] + Whh_de[c][k]
__global__ void k_prep_de(const float* __restrict__ Wih_de, const float* __restrict__ Whh_de,
                          _Float16* __restrict__ Wz, _Float16* __restrict__ Wr) {
    int i = blockIdx.x * blockDim.x + threadIdx.x;   // over 512*512
    int cc = i >> 9, kk = i & 511;
    Wz[i] = (_Float16)Wih_de[cc * 1024 + 512 + kk];
    Wr[i] = (_Float16)(Wih_de[cc * 1024 + kk] + Whh_de[i]);
}

__global__ void k_prep_bias(const float* __restrict__ a, const float* __restrict__ b,
                            float* __restrict__ o) {
    int i = threadIdx.x;
    o[i] = a[i] + b[i];
}

// ---------------- GEMM: C[M,N] = A[M,K] @ Bt[N,K]^T + bias[N] ----------------
#define BM 128
#define BN 128
#define BK 32
#define LDT 40   // padded LDS row stride in f16 units

__global__ __launch_bounds__(256) void k_gemm(
    const _Float16* __restrict__ A, const _Float16* __restrict__ Bt,
    const float* __restrict__ bias,
    float* __restrict__ Cf, _Float16* __restrict__ Ch,
    int M, int N, int K) {
    __shared__ _Float16 Al[BM * LDT];
    __shared__ _Float16 Bl[BN * LDT];
    const int tid = threadIdx.x;
    const int bm = blockIdx.x * BM, bn = blockIdx.y * BN;
    const int wid = tid >> 6, lane = tid & 63;
    const int wm = (wid >> 1) * 64, wn = (wid & 1) * 64;
    const int l15 = lane & 15, l4 = lane >> 4;

    f4_t acc[4][4];
    #pragma unroll
    for (int i = 0; i < 4; ++i)
        #pragma unroll
        for (int j = 0; j < 4; ++j) {
            f4_t zz = {0.f, 0.f, 0.f, 0.f};
            acc[i][j] = zz;
        }

    const int r = tid >> 1, hf = tid & 1;
    const h8_t* gA0 = (const h8_t*)(A + (size_t)(bm + r) * K);
    const h8_t* gB0 = (const h8_t*)(Bt + (size_t)(bn + r) * K);

    for (int k0 = 0; k0 < K; k0 += BK) {
        __syncthreads();
        int kf = (k0 >> 3) + hf * 2;
        h8_t a0 = gA0[kf], a1 = gA0[kf + 1];
        h8_t b0 = gB0[kf], b1 = gB0[kf + 1];
        *(h8_t*)&Al[r * LDT + hf * 16]     = a0;
        *(h8_t*)&Al[r * LDT + hf * 16 + 8] = a1;
        *(h8_t*)&Bl[r * LDT + hf * 16]     = b0;
        *(h8_t*)&Bl[r * LDT + hf * 16 + 8] = b1;
        __syncthreads();
        h8_t af[4], bf[4];
        #pragma unroll
        for (int i = 0; i < 4; ++i) af[i] = *(const h8_t*)&Al[(wm + i * 16 + l15) * LDT + l4 * 8];
        #pragma unroll
        for (int j = 0; j < 4; ++j) bf[j] = *(const h8_t*)&Bl[(wn + j * 16 + l15) * LDT + l4 * 8];
        #pragma unroll
        for (int i = 0; i < 4; ++i)
            #pragma unroll
            for (int j = 0; j < 4; ++j)
                acc[i][j] = __builtin_amdgcn_mfma_f32_16x16x32_f16(af[i], bf[j], acc[i][j], 0, 0, 0);
    }

    #pragma unroll
    for (int i = 0; i < 4; ++i) {
        int m0 = bm + wm + i * 16 + l4 * 4;
        #pragma unroll
        for (int j = 0; j < 4; ++j) {
            int n0 = bn + wn + j * 16 + l15;
            float bb = bias ? bias[n0] : 0.f;
            #pragma unroll
            for (int rr = 0; rr < 4; ++rr) {
                float v = acc[i][j][rr] + bb;
                size_t off = (size_t)(m0 + rr) * N + n0;
                if (Cf) Cf[off] = v;
                if (Ch) Ch[off] = (_Float16)v;
            }
        }
    }
}

// ---------------- persistent-weight RNN ----------------
// One block per batch row, 512 threads, __launch_bounds__(512,2) -> VGPR cap 256.
// Thread (c2 = tid&255, s = tid>>8) owns output rows {c2, c2+256} over K-half s
// (k in [s*256, s*256+256)): 512 MACs/thread/step.
// Weights: 26 h8-chunks per row in VGPRs (wv[52], 208 regs, static idx) +
// 6 h8-chunks per row in LDS laid out [chunk][tid] (16B/lane consecutive -> conflict-free).
// h[512] f16 in LDS (broadcast reads); f32 partial[512] for the s=1 -> s=0 reduction.
// 2 barriers per step.
__global__ __launch_bounds__(512, 2) void k_rnn(
    const _Float16* __restrict__ W,
    const _Float16* __restrict__ pre,   // [B,T,H] f16 pre-activation
    _Float16* __restrict__ out) {       // [B,T,H] f16 hidden states
    __shared__ __align__(16) uint4 WL4[12 * 512];          // 96 KiB weight spill-to-LDS
    __shared__ __align__(16) unsigned short h_lds[H_];     // h as f16 bits
    __shared__ float partial[H_];

    const int tid = threadIdx.x;
    const int c2 = tid & 255;
    const int s = tid >> 8;          // wave-uniform (waves 0-3: s=0, waves 4-7: s=1)
    const int b = blockIdx.x;

    const h8_t* g0 = (const h8_t*)(W + (size_t)c2 * H_ + s * 256);
    const h8_t* g1 = (const h8_t*)(W + (size_t)(c2 + 256) * H_ + s * 256);
    h8_t wv[52];
    #pragma unroll
    for (int j = 0; j < 26; ++j) { wv[j] = g0[j]; wv[26 + j] = g1[j]; }
    #pragma unroll
    for (int q = 0; q < 6; ++q) {
        WL4[q * 512 + tid]       = __builtin_bit_cast(uint4, g0[26 + q]);
        WL4[(6 + q) * 512 + tid] = __builtin_bit_cast(uint4, g1[26 + q]);
    }
    if (tid < 64) ((uint4*)h_lds)[tid] = make_uint4(0u, 0u, 0u, 0u);
    __syncthreads();

    const size_t base0 = (size_t)b * T_ * H_ + c2;
    float p0 = 0.f, p1 = 0.f;
    if (!s) { p0 = (float)pre[base0]; p1 = (float)pre[base0 + 256]; }

    for (int t = 0; t < T_; ++t) {
        int tn = (t + 1 < T_) ? t + 1 : t;
        _Float16 pn0 = (_Float16)0.f, pn1 = (_Float16)0.f;
        if (!s) {
            pn0 = pre[base0 + (size_t)tn * H_];
            pn1 = pre[base0 + (size_t)tn * H_ + 256];
        }

        float a0 = 0.f, a1 = 0.f;
        const uint4* hv = ((const uint4*)h_lds) + s * 32;   // this thread's K-half of h
        #pragma unroll
        for (int j = 0; j < 26; ++j) {
            uint4 hh = hv[j];
            dot8(a0, __builtin_bit_cast(uint4, wv[j]), hh);
            dot8(a1, __builtin_bit_cast(uint4, wv[26 + j]), hh);
        }
        #pragma unroll
        for (int q = 0; q < 6; ++q) {
            uint4 hh = hv[26 + q];
            uint4 w0 = WL4[q * 512 + tid];
            uint4 w1 = WL4[(6 + q) * 512 + tid];
            dot8(a0, w0, hh);
            dot8(a1, w1, hh);
        }

        if (s) {
            partial[c2] = a0;
            partial[c2 + 256] = a1;
        }
        __syncthreads();
        if (!s) {
            float h0 = tanhf(a0 + partial[c2] + p0);
            float h1 = tanhf(a1 + partial[c2 + 256] + p1);
            _Float16 hh0 = (_Float16)h0, hh1 = (_Float16)h1;
            out[base0 + (size_t)t * H_] = hh0;
            out[base0 + (size_t)t * H_ + 256] = hh1;
            h_lds[c2] = __builtin_bit_cast(unsigned short, hh0);
            h_lds[c2 + 256] = __builtin_bit_cast(unsigned short, hh1);
        }
        __syncthreads();
        p0 = (float)pn0; p1 = (float)pn1;
    }
}

// ---------------- reparameterize: z = eps * exp(lv/2) + mu ----------------
__global__ void k_z(const float* __restrict__ mu, const float* __restrict__ lv,
                    const float* __restrict__ eps, _Float16* __restrict__ z, int n4) {
    int i = blockIdx.x * blockDim.x + threadIdx.x;
    if (i >= n4) return;
    f4_t m = ((const f4_t*)mu)[i];
    f4_t l = ((const f4_t*)lv)[i];
    f4_t e = ((const f4_t*)eps)[i];
    h4_t r;
    #pragma unroll
    for (int j = 0; j < 4; ++j) r[j] = (_Float16)(e[j] * expf(l[j] * 0.5f) + m[j]);
    ((h4_t*)z)[i] = r;
}

// ---------------- launch ----------------
extern "C" void kernel_launch(void* const* d_in, const int* in_sizes, int n_in,
                              void* d_out, int out_size, void* d_ws, size_t ws_size,
                              hipStream_t stream) {
    const float* x      = (const float*)d_in[0];
    const float* eps    = (const float*)d_in[1];
    const float* Wih_en = (const float*)d_in[2];
    const float* Whh_en = (const float*)d_in[3];
    const float* bih_en = (const float*)d_in[4];
    const float* bhh_en = (const float*)d_in[5];
    const float* W_mu   = (const float*)d_in[6];
    const float* b_mu   = (const float*)d_in[7];
    const float* W_lv   = (const float*)d_in[8];
    const float* b_lv   = (const float*)d_in[9];
    const float* Wih_de = (const float*)d_in[10];
    const float* Whh_de = (const float*)d_in[11];
    const float* bih_de = (const float*)d_in[12];
    const float* bhh_de = (const float*)d_in[13];
    const float* W_mux  = (const float*)d_in[14];
    const float* b_mux  = (const float*)d_in[15];
    const float* W_lvx  = (const float*)d_in[16];
    const float* b_lvx  = (const float*)d_in[17];
    float* out = (float*)d_out;

    char* ws = (char*)d_ws;
    _Float16* Wih_en_h = (_Float16*)(ws + 0);        // 512*128
    _Float16* Whh_en_h = (_Float16*)(ws + 131072);   // 512*512
    _Float16* W_mu_h   = (_Float16*)(ws + 655360);
    _Float16* W_lv_h   = (_Float16*)(ws + 1179648);
    _Float16* Wz_h     = (_Float16*)(ws + 1703936);
    _Float16* Wr_h     = (_Float16*)(ws + 2228224);
    _Float16* Wmux_h   = (_Float16*)(ws + 2752512);  // 128*512
    _Float16* Wlvx_h   = (_Float16*)(ws + 2883584);
    float*    benc     = (float*)(ws + 3014656);     // 512 f32
    float*    bdec     = (float*)(ws + 3016704);
    _Float16* x_h      = (_Float16*)(ws + 4194304);  // 64*512*128
    _Float16* pre_h    = (_Float16*)(ws + 12582912); // 64*512*512  (pre_en, then pre_de)
    _Float16* act_h    = (_Float16*)(ws + 46137344); // 64*512*512  (y, then decoder outputs)
    _Float16* z_h      = (_Float16*)(ws + 79691776); // 64*512*512

    const int thr = 256;
    k_cast_f16<<<(65536 + thr - 1) / thr, thr, 0, stream>>>(Wih_en, Wih_en_h, 65536);
    k_cast_f16<<<(262144 + thr - 1) / thr, thr, 0, stream>>>(Whh_en, Whh_en_h, 262144);
    k_cast_f16<<<(262144 + thr - 1) / thr, thr, 0, stream>>>(W_mu, W_mu_h, 262144);
    k_cast_f16<<<(262144 + thr - 1) / thr, thr, 0, stream>>>(W_lv, W_lv_h, 262144);
    k_cast_f16<<<(65536 + thr - 1) / thr, thr, 0, stream>>>(W_mux, Wmux_h, 65536);
    k_cast_f16<<<(65536 + thr - 1) / thr, thr, 0, stream>>>(W_lvx, Wlvx_h, 65536);
    k_cast_f16<<<(4194304 + thr - 1) / thr, thr, 0, stream>>>(x, x_h, 4194304);
    k_prep_de<<<262144 / thr, thr, 0, stream>>>(Wih_de, Whh_de, Wz_h, Wr_h);
    k_prep_bias<<<1, 512, 0, stream>>>(bih_en, bhh_en, benc);
    k_prep_bias<<<1, 512, 0, stream>>>(bih_de, bhh_de, bdec);

    dim3 gFull(32768 / BM, 512 / BN);   // 256 x 4
    dim3 gNarrow(32768 / BM, 1);        // 256 x 1 (N=128)

    // encoder pre-activation: x @ Wih_en^T + (bih_en + bhh_en)
    k_gemm<<<gFull, 256, 0, stream>>>(x_h, Wih_en_h, benc, nullptr, pre_h, 32768, 512, 128);
    // encoder recurrence -> y
    k_rnn<<<64, 512, 0, stream>>>(Whh_en_h, pre_h, act_h);
    // mu_post, logsigma2_post
    k_gemm<<<gFull, 256, 0, stream>>>(act_h, W_mu_h, b_mu, out, nullptr, 32768, 512, 512);
    k_gemm<<<gFull, 256, 0, stream>>>(act_h, W_lv_h, b_lv, out + 16777216, nullptr, 32768, 512, 512);
    // z = eps * exp(lv/2) + mu
    k_z<<<4194304 / thr, thr, 0, stream>>>(out, out + 16777216, eps, z_h, 4194304);
    // decoder pre-activation: z @ Wz^T + (bih_de + bhh_de)
    k_gemm<<<gFull, 256, 0, stream>>>(z_h, Wz_h, bdec, nullptr, pre_h, 32768, 512, 512);
    // decoder recurrence -> outputs (reuse act_h; y is dead)
    k_rnn<<<64, 512, 0, stream>>>(Wr_h, pre_h, act_h);
    // output projections
    k_gemm<<<gNarrow, 256, 0, stream>>>(act_h, Wmux_h, b_mux, out + 33554432, nullptr, 32768, 128, 512);
    k_gemm<<<gNarrow, 256, 0, stream>>>(act_h, Wlvx_h, b_lvx, out + 37748736, nullptr, 32768, 128, 512);
}

// Round 3
// 1807.093 us; speedup vs baseline: 1.1482x; 1.0001x over previous
//
#include <hip/hip_runtime.h>

typedef _Float16 h2_t __attribute__((ext_vector_type(2)));
typedef _Float16 h4_t __attribute__((ext_vector_type(4)));
typedef _Float16 h8_t __attribute__((ext_vector_type(8)));
typedef float    f4_t __attribute__((ext_vector_type(4)));

#define B_  64
#define T_  512
#define F_  128
#define H_  512

static __device__ __forceinline__ float fdot2f(h2_t a, h2_t b, float c) {
#if __has_builtin(__builtin_amdgcn_fdot2)
    return __builtin_amdgcn_fdot2(a, b, c, false);
#else
    return c + (float)a.x * (float)b.x + (float)a.y * (float)b.y;
#endif
}

static __device__ __forceinline__ void dot8(float& acc, uint4 w, uint4 h) {
    acc = fdot2f(__builtin_bit_cast(h2_t, w.x), __builtin_bit_cast(h2_t, h.x), acc);
    acc = fdot2f(__builtin_bit_cast(h2_t, w.y), __builtin_bit_cast(h2_t, h.y), acc);
    acc = fdot2f(__builtin_bit_cast(h2_t, w.z), __builtin_bit_cast(h2_t, h.z), acc);
    acc = fdot2f(__builtin_bit_cast(h2_t, w.w), __builtin_bit_cast(h2_t, h.w), acc);
}

// ---------------- prep kernels ----------------
__global__ void k_cast_f16(const float* __restrict__ src, _Float16* __restrict__ dst, int n) {
    int i = blockIdx.x * blockDim.x + threadIdx.x;
    if (i < n) dst[i] = (_Float16)src[i];
}

// Wz[c][k] = Wih_de[c][512+k];  Wr[c][k] = Wih_de[c][k] + Whh_de[c][k]
__global__ void k_prep_de(const float* __restrict__ Wih_de, const float* __restrict__ Whh_de,
                          _Float16* __restrict__ Wz, _Float16* __restrict__ Wr) {
    int i = blockIdx.x * blockDim.x + threadIdx.x;   // over 512*512
    int cc = i >> 9, kk = i & 511;
    Wz[i] = (_Float16)Wih_de[cc * 1024 + 512 + kk];
    Wr[i] = (_Float16)(Wih_de[cc * 1024 + kk] + Whh_de[i]);
}

__global__ void k_prep_bias(const float* __restrict__ a, const float* __restrict__ b,
                            float* __restrict__ o) {
    int i = threadIdx.x;
    o[i] = a[i] + b[i];
}

// ---------------- GEMM: C[M,N] = A[M,K] @ Bt[N,K]^T + bias[N] ----------------
#define BM 128
#define BN 128
#define BK 32
#define LDT 40   // padded LDS row stride in f16 units

__global__ __launch_bounds__(256) void k_gemm(
    const _Float16* __restrict__ A, const _Float16* __restrict__ Bt,
    const float* __restrict__ bias,
    float* __restrict__ Cf, _Float16* __restrict__ Ch,
    int M, int N, int K) {
    __shared__ _Float16 Al[BM * LDT];
    __shared__ _Float16 Bl[BN * LDT];
    const int tid = threadIdx.x;
    const int bm = blockIdx.x * BM, bn = blockIdx.y * BN;
    const int wid = tid >> 6, lane = tid & 63;
    const int wm = (wid >> 1) * 64, wn = (wid & 1) * 64;
    const int l15 = lane & 15, l4 = lane >> 4;

    f4_t acc[4][4];
    #pragma unroll
    for (int i = 0; i < 4; ++i)
        #pragma unroll
        for (int j = 0; j < 4; ++j) {
            f4_t zz = {0.f, 0.f, 0.f, 0.f};
            acc[i][j] = zz;
        }

    const int r = tid >> 1, hf = tid & 1;
    const h8_t* gA0 = (const h8_t*)(A + (size_t)(bm + r) * K);
    const h8_t* gB0 = (const h8_t*)(Bt + (size_t)(bn + r) * K);

    for (int k0 = 0; k0 < K; k0 += BK) {
        __syncthreads();
        int kf = (k0 >> 3) + hf * 2;
        h8_t a0 = gA0[kf], a1 = gA0[kf + 1];
        h8_t b0 = gB0[kf], b1 = gB0[kf + 1];
        *(h8_t*)&Al[r * LDT + hf * 16]     = a0;
        *(h8_t*)&Al[r * LDT + hf * 16 + 8] = a1;
        *(h8_t*)&Bl[r * LDT + hf * 16]     = b0;
        *(h8_t*)&Bl[r * LDT + hf * 16 + 8] = b1;
        __syncthreads();
        h8_t af[4], bf[4];
        #pragma unroll
        for (int i = 0; i < 4; ++i) af[i] = *(const h8_t*)&Al[(wm + i * 16 + l15) * LDT + l4 * 8];
        #pragma unroll
        for (int j = 0; j < 4; ++j) bf[j] = *(const h8_t*)&Bl[(wn + j * 16 + l15) * LDT + l4 * 8];
        #pragma unroll
        for (int i = 0; i < 4; ++i)
            #pragma unroll
            for (int j = 0; j < 4; ++j)
                acc[i][j] = __builtin_amdgcn_mfma_f32_16x16x32_f16(af[i], bf[j], acc[i][j], 0, 0, 0);
    }

    #pragma unroll
    for (int i = 0; i < 4; ++i) {
        int m0 = bm + wm + i * 16 + l4 * 4;
        #pragma unroll
        for (int j = 0; j < 4; ++j) {
            int n0 = bn + wn + j * 16 + l15;
            float bb = bias ? bias[n0] : 0.f;
            #pragma unroll
            for (int rr = 0; rr < 4; ++rr) {
                float v = acc[i][j][rr] + bb;
                size_t off = (size_t)(m0 + rr) * N + n0;
                if (Cf) Cf[off] = v;
                if (Ch) Ch[off] = (_Float16)v;
            }
        }
    }
}

// ---------------- persistent-weight RNN ----------------
// One block per batch row, 512 threads, pinned to EXACTLY 2 waves/SIMD
// (amdgpu_waves_per_eu(2,2)) so the register budget is 256 VGPRs/wave and the
// weight array stays register-resident (round-2 failure: compiler targeted
// 4 waves/SIMD -> 128 VGPRs -> weights re-streamed from L2 every step, 21 TB/s).
// Thread (c2 = tid&255, s = tid>>8) owns output rows {c2, c2+256} over K-half s:
// 512 MACs/thread/step. Weights: 26 h8-chunks/row in VGPRs (wv[52], 208 regs,
// static idx) + 6 h8-chunks/row in LDS [chunk][tid] (16B/lane -> conflict-free).
// h[512] f16 in LDS (broadcast reads); f32 partial[512] for s=1 -> s=0 reduction.
__global__ __attribute__((amdgpu_flat_work_group_size(512, 512), amdgpu_waves_per_eu(2, 2)))
void k_rnn(
    const _Float16* __restrict__ W,
    const _Float16* __restrict__ pre,   // [B,T,H] f16 pre-activation
    _Float16* __restrict__ out) {       // [B,T,H] f16 hidden states
    __shared__ __align__(16) uint4 WL4[12 * 512];          // 96 KiB weight spill-to-LDS
    __shared__ __align__(16) unsigned short h_lds[H_];     // h as f16 bits
    __shared__ float partial[H_];

    const int tid = threadIdx.x;
    const int c2 = tid & 255;
    const int s = tid >> 8;          // wave-uniform (waves 0-3: s=0, waves 4-7: s=1)
    const int b = blockIdx.x;

    const h8_t* g0 = (const h8_t*)(W + (size_t)c2 * H_ + s * 256);
    const h8_t* g1 = (const h8_t*)(W + (size_t)(c2 + 256) * H_ + s * 256);
    h8_t wv[52];
    #pragma unroll
    for (int j = 0; j < 26; ++j) { wv[j] = g0[j]; wv[26 + j] = g1[j]; }
    #pragma unroll
    for (int q = 0; q < 6; ++q) {
        WL4[q * 512 + tid]       = __builtin_bit_cast(uint4, g0[26 + q]);
        WL4[(6 + q) * 512 + tid] = __builtin_bit_cast(uint4, g1[26 + q]);
    }
    if (tid < 64) ((uint4*)h_lds)[tid] = make_uint4(0u, 0u, 0u, 0u);
    __syncthreads();

    const size_t base0 = (size_t)b * T_ * H_ + c2;
    float p0 = 0.f, p1 = 0.f;
    if (!s) { p0 = (float)pre[base0]; p1 = (float)pre[base0 + 256]; }

    for (int t = 0; t < T_; ++t) {
        int tn = (t + 1 < T_) ? t + 1 : t;
        _Float16 pn0 = (_Float16)0.f, pn1 = (_Float16)0.f;
        if (!s) {
            pn0 = pre[base0 + (size_t)tn * H_];
            pn1 = pre[base0 + (size_t)tn * H_ + 256];
        }

        float a0 = 0.f, a1 = 0.f;
        const uint4* hv = ((const uint4*)h_lds) + s * 32;   // this thread's K-half of h
        #pragma unroll
        for (int j = 0; j < 26; ++j) {
            uint4 hh = hv[j];
            dot8(a0, __builtin_bit_cast(uint4, wv[j]), hh);
            dot8(a1, __builtin_bit_cast(uint4, wv[26 + j]), hh);
        }
        #pragma unroll
        for (int q = 0; q < 6; ++q) {
            uint4 hh = hv[26 + q];
            uint4 w0 = WL4[q * 512 + tid];
            uint4 w1 = WL4[(6 + q) * 512 + tid];
            dot8(a0, w0, hh);
            dot8(a1, w1, hh);
        }

        if (s) {
            partial[c2] = a0;
            partial[c2 + 256] = a1;
        }
        __syncthreads();
        if (!s) {
            float h0 = tanhf(a0 + partial[c2] + p0);
            float h1 = tanhf(a1 + partial[c2 + 256] + p1);
            _Float16 hh0 = (_Float16)h0, hh1 = (_Float16)h1;
            out[base0 + (size_t)t * H_] = hh0;
            out[base0 + (size_t)t * H_ + 256] = hh1;
            h_lds[c2] = __builtin_bit_cast(unsigned short, hh0);
            h_lds[c2 + 256] = __builtin_bit_cast(unsigned short, hh1);
        }
        __syncthreads();
        p0 = (float)pn0; p1 = (float)pn1;
    }
}

// ---------------- reparameterize: z = eps * exp(lv/2) + mu ----------------
__global__ void k_z(const float* __restrict__ mu, const float* __restrict__ lv,
                    const float* __restrict__ eps, _Float16* __restrict__ z, int n4) {
    int i = blockIdx.x * blockDim.x + threadIdx.x;
    if (i >= n4) return;
    f4_t m = ((const f4_t*)mu)[i];
    f4_t l = ((const f4_t*)lv)[i];
    f4_t e = ((const f4_t*)eps)[i];
    h4_t r;
    #pragma unroll
    for (int j = 0; j < 4; ++j) r[j] = (_Float16)(e[j] * expf(l[j] * 0.5f) + m[j]);
    ((h4_t*)z)[i] = r;
}

// ---------------- launch ----------------
extern "C" void kernel_launch(void* const* d_in, const int* in_sizes, int n_in,
                              void* d_out, int out_size, void* d_ws, size_t ws_size,
                              hipStream_t stream) {
    const float* x      = (const float*)d_in[0];
    const float* eps    = (const float*)d_in[1];
    const float* Wih_en = (const float*)d_in[2];
    const float* Whh_en = (const float*)d_in[3];
    const float* bih_en = (const float*)d_in[4];
    const float* bhh_en = (const float*)d_in[5];
    const float* W_mu   = (const float*)d_in[6];
    const float* b_mu   = (const float*)d_in[7];
    const float* W_lv   = (const float*)d_in[8];
    const float* b_lv   = (const float*)d_in[9];
    const float* Wih_de = (const float*)d_in[10];
    const float* Whh_de = (const float*)d_in[11];
    const float* bih_de = (const float*)d_in[12];
    const float* bhh_de = (const float*)d_in[13];
    const float* W_mux  = (const float*)d_in[14];
    const float* b_mux  = (const float*)d_in[15];
    const float* W_lvx  = (const float*)d_in[16];
    const float* b_lvx  = (const float*)d_in[17];
    float* out = (float*)d_out;

    char* ws = (char*)d_ws;
    _Float16* Wih_en_h = (_Float16*)(ws + 0);        // 512*128
    _Float16* Whh_en_h = (_Float16*)(ws + 131072);   // 512*512
    _Float16* W_mu_h   = (_Float16*)(ws + 655360);
    _Float16* W_lv_h   = (_Float16*)(ws + 1179648);
    _Float16* Wz_h     = (_Float16*)(ws + 1703936);
    _Float16* Wr_h     = (_Float16*)(ws + 2228224);
    _Float16* Wmux_h   = (_Float16*)(ws + 2752512);  // 128*512
    _Float16* Wlvx_h   = (_Float16*)(ws + 2883584);
    float*    benc     = (float*)(ws + 3014656);     // 512 f32
    float*    bdec     = (float*)(ws + 3016704);
    _Float16* x_h      = (_Float16*)(ws + 4194304);  // 64*512*128
    _Float16* pre_h    = (_Float16*)(ws + 12582912); // 64*512*512  (pre_en, then pre_de)
    _Float16* act_h    = (_Float16*)(ws + 46137344); // 64*512*512  (y, then decoder outputs)
    _Float16* z_h      = (_Float16*)(ws + 79691776); // 64*512*512

    const int thr = 256;
    k_cast_f16<<<(65536 + thr - 1) / thr, thr, 0, stream>>>(Wih_en, Wih_en_h, 65536);
    k_cast_f16<<<(262144 + thr - 1) / thr, thr, 0, stream>>>(Whh_en, Whh_en_h, 262144);
    k_cast_f16<<<(262144 + thr - 1) / thr, thr, 0, stream>>>(W_mu, W_mu_h, 262144);
    k_cast_f16<<<(262144 + thr - 1) / thr, thr, 0, stream>>>(W_lv, W_lv_h, 262144);
    k_cast_f16<<<(65536 + thr - 1) / thr, thr, 0, stream>>>(W_mux, Wmux_h, 65536);
    k_cast_f16<<<(65536 + thr - 1) / thr, thr, 0, stream>>>(W_lvx, Wlvx_h, 65536);
    k_cast_f16<<<(4194304 + thr - 1) / thr, thr, 0, stream>>>(x, x_h, 4194304);
    k_prep_de<<<262144 / thr, thr, 0, stream>>>(Wih_de, Whh_de, Wz_h, Wr_h);
    k_prep_bias<<<1, 512, 0, stream>>>(bih_en, bhh_en, benc);
    k_prep_bias<<<1, 512, 0, stream>>>(bih_de, bhh_de, bdec);

    dim3 gFull(32768 / BM, 512 / BN);   // 256 x 4
    dim3 gNarrow(32768 / BM, 1);        // 256 x 1 (N=128)

    // encoder pre-activation: x @ Wih_en^T + (bih_en + bhh_en)
    k_gemm<<<gFull, 256, 0, stream>>>(x_h, Wih_en_h, benc, nullptr, pre_h, 32768, 512, 128);
    // encoder recurrence -> y
    k_rnn<<<64, 512, 0, stream>>>(Whh_en_h, pre_h, act_h);
    // mu_post, logsigma2_post
    k_gemm<<<gFull, 256, 0, stream>>>(act_h, W_mu_h, b_mu, out, nullptr, 32768, 512, 512);
    k_gemm<<<gFull, 256, 0, stream>>>(act_h, W_lv_h, b_lv, out + 16777216, nullptr, 32768, 512, 512);
    // z = eps * exp(lv/2) + mu
    k_z<<<4194304 / thr, thr, 0, stream>>>(out, out + 16777216, eps, z_h, 4194304);
    // decoder pre-activation: z @ Wz^T + (bih_de + bhh_de)
    k_gemm<<<gFull, 256, 0, stream>>>(z_h, Wz_h, bdec, nullptr, pre_h, 32768, 512, 512);
    // decoder recurrence -> outputs (reuse act_h; y is dead)
    k_rnn<<<64, 512, 0, stream>>>(Wr_h, pre_h, act_h);
    // output projections
    k_gemm<<<gNarrow, 256, 0, stream>>>(act_h, Wmux_h, b_mux, out + 33554432, nullptr, 32768, 128, 512);
    k_gemm<<<gNarrow, 256, 0, stream>>>(act_h, Wlvx_h, b_lvx, out + 37748736, nullptr, 32768, 128, 512);
}